// Round 1
// baseline (864.200 us; speedup 1.0000x reference)
//
#include <hip/hip_runtime.h>
#include <hip/hip_bf16.h>

typedef __bf16 bf16x8 __attribute__((ext_vector_type(8)));
typedef __bf16 bf16x4v __attribute__((ext_vector_type(4)));
typedef float f32x4 __attribute__((ext_vector_type(4)));

#define MFMA(a, b, c) __builtin_amdgcn_mfma_f32_16x16x32_bf16((a), (b), (c), 0, 0, 0)

#define NEG_BIG (-1e30f)

// LDS strides (elements) -- all multiples of 8 so 16B ds_read_b128 frags stay aligned
#define XO_LD 264  // x / o tile [64][264]
#define W_LD 136   // W half-K stage [96][136]
#define QK_LD 40   // q,k [64][40]
#define VT_LD 72   // vT [32][72]
#define P_LD 72    // p [64][72]

// ---------------------------------------------------------------- prep -----
__global__ __launch_bounds__(256) void prep_kernel(
    const float* __restrict__ w_qkv, const float* __restrict__ w_out,
    const float* __restrict__ rel_emb, const int* __restrict__ rel_idx,
    __bf16* __restrict__ wqkv_b, __bf16* __restrict__ wout_b,
    float* __restrict__ bias) {
  const float kScale = 0.17677669529663687f;  // 32^-0.5, folded into Wq
  int idx = blockIdx.x * 256 + threadIdx.x;
  if (idx < 196608) {  // w_qkv (768x256) -> bf16, q rows pre-scaled
    float v = w_qkv[idx];
    if (idx < 65536) v *= kScale;
    wqkv_b[idx] = (__bf16)v;
  } else if (idx < 262144) {  // w_out (256x256) -> bf16
    int j = idx - 196608;
    wout_b[j] = (__bf16)w_out[j];
  } else if (idx < 294912) {  // bias_pad[h][64][64], -1e30 beyond 49
    int j = idx - 262144;
    int h = j >> 12, i = (j >> 6) & 63, c = j & 63;
    float v = NEG_BIG;
    if (i < 49 && c < 49) v = rel_emb[rel_idx[i * 49 + c] * 8 + h];
    bias[j] = v;
  }
}

// ---------------------------------------------------------------- main -----
// One block per window. 256 threads = 4 waves; wave w owns M-tile rows
// [16w,16w+16). MFMA 16x16x32 bf16 layouts (HW-verified per guide):
//   A: m=lane&15, k=quad*8+j   B: n=lane&15, k=quad*8+j
//   C/D: col=lane&15, row=quad*4+reg
__global__ __launch_bounds__(256, 2) void attn_kernel(
    const float* __restrict__ x, const __bf16* __restrict__ wqkv,
    const __bf16* __restrict__ wout, const float* __restrict__ bias,
    float* __restrict__ out) {
  __shared__ __attribute__((aligned(16))) __bf16 s_xo[64 * XO_LD];  // x then o
  __shared__ __attribute__((aligned(16))) __bf16 s_r2[96 * W_LD];   // W / attn bufs

  __bf16* q_s = s_r2;          // [64][40]
  __bf16* k_s = s_r2 + 2560;   // [64][40]
  __bf16* vt_s = s_r2 + 5120;  // [32][72] (v transposed: [dh][token])
  __bf16* p_s = s_r2 + 7424;   // [64][72]

  const int tid = threadIdx.x;
  const int wave = tid >> 6;
  const int lane = tid & 63;
  const int quad = lane >> 4;
  const int l16 = lane & 15;
  const int i0 = wave * 16 + quad * 4;  // C/D row base
  const int am = wave * 16 + l16;       // A-operand row

  const f32x4 fzero = {0.f, 0.f, 0.f, 0.f};

  // ---- stage x window (49x256 fp32 -> bf16), zero pad rows 49..63
  {
    const float4* xg = (const float4*)(x + (size_t)blockIdx.x * 12544);
    for (int i = tid; i < 3136; i += 256) {
      float4 v = xg[i];
      int row = i >> 6, c4 = (i & 63) << 2;
      bf16x4v t;
      t[0] = (__bf16)v.x; t[1] = (__bf16)v.y; t[2] = (__bf16)v.z; t[3] = (__bf16)v.w;
      *(bf16x4v*)&s_xo[row * XO_LD + c4] = t;
    }
    bf16x4v z;
    z[0] = z[1] = z[2] = z[3] = (__bf16)0.0f;
    for (int i = tid; i < 960; i += 256) {
      int row = 49 + (i >> 6), c4 = (i & 63) << 2;
      *(bf16x4v*)&s_xo[row * XO_LD + c4] = z;
    }
  }
  __syncthreads();

  // ---- preload x A-fragments (K=256 -> 8 frags), reused for all 8 heads
  bf16x8 afr[8];
  {
    const __bf16* base = &s_xo[am * XO_LD + quad * 8];
#pragma unroll
    for (int kk = 0; kk < 8; ++kk) afr[kk] = *(const bf16x8*)(base + kk * 32);
  }

  // ---- per-head fused attention
  for (int h = 0; h < 8; ++h) {
    f32x4 acc[6];
#pragma unroll
    for (int t = 0; t < 6; ++t) acc[t] = fzero;

    // qkv GEMM: C(64x96) = x(64x256) @ W^T, staged in two K=128 halves
#pragma unroll
    for (int kh = 0; kh < 2; ++kh) {
      __syncthreads();  // previous contents of s_r2 fully consumed
      for (int i = tid; i < 1536; i += 256) {
        int lr = i >> 4, c = (i & 15) * 8;
        int grow = (lr >> 5) * 256 + h * 32 + (lr & 31);  // q|k|v row
        *(bf16x8*)&s_r2[lr * W_LD + c] =
            *(const bf16x8*)&wqkv[grow * 256 + kh * 128 + c];
      }
      __syncthreads();
#pragma unroll
      for (int k2 = 0; k2 < 4; ++k2) {
        bf16x8 a = afr[kh * 4 + k2];
#pragma unroll
        for (int t = 0; t < 6; ++t) {
          bf16x8 b = *(const bf16x8*)&s_r2[(t * 16 + l16) * W_LD + k2 * 32 + quad * 8];
          acc[t] = MFMA(a, b, acc[t]);
        }
      }
    }
    __syncthreads();

    // scatter q,k row-major and v transposed, bf16
#pragma unroll
    for (int t = 0; t < 2; ++t) {
#pragma unroll
      for (int r = 0; r < 4; ++r) {
        q_s[(i0 + r) * QK_LD + t * 16 + l16] = (__bf16)acc[t][r];
        k_s[(i0 + r) * QK_LD + t * 16 + l16] = (__bf16)acc[2 + t][r];
      }
      bf16x4v pv;
#pragma unroll
      for (int r = 0; r < 4; ++r) pv[r] = (__bf16)acc[4 + t][r];
      *(bf16x4v*)&vt_s[(t * 16 + l16) * VT_LD + i0] = pv;
    }
    __syncthreads();

    // sim = q.k^T + bias (acc INITIALIZED from bias table; K=32 -> 1 MFMA/tile)
    f32x4 s[4];
    {
      const float* bb = bias + (h << 12);
#pragma unroll
      for (int nt = 0; nt < 4; ++nt)
#pragma unroll
        for (int r = 0; r < 4; ++r) s[nt][r] = bb[(i0 + r) * 64 + nt * 16 + l16];
      bf16x8 a = *(const bf16x8*)&q_s[am * QK_LD + quad * 8];
#pragma unroll
      for (int nt = 0; nt < 4; ++nt) {
        bf16x8 b = *(const bf16x8*)&k_s[(nt * 16 + l16) * QK_LD + quad * 8];
        s[nt] = MFMA(a, b, s[nt]);
      }
    }

    // row softmax: row lives in one 16-lane quad -> shfl_xor 1,2,4,8
#pragma unroll
    for (int r = 0; r < 4; ++r) {
      float mx = fmaxf(fmaxf(s[0][r], s[1][r]), fmaxf(s[2][r], s[3][r]));
      mx = fmaxf(mx, __shfl_xor(mx, 1));
      mx = fmaxf(mx, __shfl_xor(mx, 2));
      mx = fmaxf(mx, __shfl_xor(mx, 4));
      mx = fmaxf(mx, __shfl_xor(mx, 8));
      float e0 = __expf(s[0][r] - mx), e1 = __expf(s[1][r] - mx);
      float e2 = __expf(s[2][r] - mx), e3 = __expf(s[3][r] - mx);
      float sm = e0 + e1 + e2 + e3;
      sm += __shfl_xor(sm, 1);
      sm += __shfl_xor(sm, 2);
      sm += __shfl_xor(sm, 4);
      sm += __shfl_xor(sm, 8);
      float rs = 1.0f / sm;
      int row = i0 + r;
      p_s[row * P_LD + l16] = (__bf16)(e0 * rs);
      p_s[row * P_LD + 16 + l16] = (__bf16)(e1 * rs);
      p_s[row * P_LD + 32 + l16] = (__bf16)(e2 * rs);
      p_s[row * P_LD + 48 + l16] = (__bf16)(e3 * rs);
    }
    __syncthreads();

    // o_h = P(64x64) @ V(64x32)
    f32x4 oa[2];
    oa[0] = fzero;
    oa[1] = fzero;
#pragma unroll
    for (int kk = 0; kk < 2; ++kk) {
      bf16x8 a = *(const bf16x8*)&p_s[am * P_LD + kk * 32 + quad * 8];
#pragma unroll
      for (int t = 0; t < 2; ++t) {
        bf16x8 b = *(const bf16x8*)&vt_s[(t * 16 + l16) * VT_LD + kk * 32 + quad * 8];
        oa[t] = MFMA(a, b, oa[t]);
      }
    }
    // o slice -> x buffer (x frags already live in VGPRs)
#pragma unroll
    for (int t = 0; t < 2; ++t)
#pragma unroll
      for (int r = 0; r < 4; ++r)
        s_xo[(i0 + r) * XO_LD + h * 32 + t * 16 + l16] = (__bf16)oa[t][r];
    // next head's kh-loop barrier protects p_s/vt_s
  }
  __syncthreads();

  // ---- out projection: out(64x256) = o @ w_out^T, 8 chunks of 32 cols
  for (int ec = 0; ec < 8; ++ec) {
    for (int i = tid; i < 1024; i += 256) {
      int lr = i >> 5, c = (i & 31) * 8;
      *(bf16x8*)&s_r2[lr * XO_LD + c] = *(const bf16x8*)&wout[(ec * 32 + lr) * 256 + c];
    }
    __syncthreads();
    f32x4 fa[2];
    fa[0] = fzero;
    fa[1] = fzero;
#pragma unroll
    for (int kk = 0; kk < 8; ++kk) {
      bf16x8 a = *(const bf16x8*)&s_xo[am * XO_LD + kk * 32 + quad * 8];
#pragma unroll
      for (int t = 0; t < 2; ++t) {
        bf16x8 b = *(const bf16x8*)&s_r2[(t * 16 + l16) * XO_LD + kk * 32 + quad * 8];
        fa[t] = MFMA(a, b, fa[t]);
      }
    }
    float* ob = out + (size_t)blockIdx.x * 12544 + ec * 32;
#pragma unroll
    for (int t = 0; t < 2; ++t)
#pragma unroll
      for (int r = 0; r < 4; ++r) {
        int row = i0 + r;
        if (row < 49) ob[row * 256 + t * 16 + l16] = fa[t][r];
      }
    __syncthreads();
  }
}

// ---------------------------------------------------------------- launch ---
extern "C" void kernel_launch(void* const* d_in, const int* in_sizes, int n_in,
                              void* d_out, int out_size, void* d_ws, size_t ws_size,
                              hipStream_t stream) {
  (void)in_sizes; (void)n_in; (void)out_size; (void)ws_size;
  const float* x = (const float*)d_in[0];
  const float* w_qkv = (const float*)d_in[1];
  const float* w_out = (const float*)d_in[2];
  const float* rel_emb = (const float*)d_in[3];
  const int* rel_idx = (const int*)d_in[4];
  float* out = (float*)d_out;

  char* ws = (char*)d_ws;
  __bf16* wqkv_b = (__bf16*)ws;                  // 768*256*2 = 393216 B
  __bf16* wout_b = (__bf16*)(ws + 393216);       // 256*256*2 = 131072 B
  float* bias = (float*)(ws + 524288);           // 8*64*64*4 = 131072 B

  prep_kernel<<<1152, 256, 0, stream>>>(w_qkv, w_out, rel_emb, rel_idx,
                                        wqkv_b, wout_b, bias);
  attn_kernel<<<4096, 256, 0, stream>>>(x, wqkv_b, wout_b, bias, out);
}

// Round 2
// 844.634 us; speedup vs baseline: 1.0232x; 1.0232x over previous
//
#include <hip/hip_runtime.h>
#include <hip/hip_bf16.h>

typedef __bf16 bf16x8 __attribute__((ext_vector_type(8)));
typedef __bf16 bf16x4v __attribute__((ext_vector_type(4)));
typedef float f32x4 __attribute__((ext_vector_type(4)));

#define MFMA(a, b, c) __builtin_amdgcn_mfma_f32_16x16x32_bf16((a), (b), (c), 0, 0, 0)
#define NEG_BIG (-1e30f)

// LDS strides (elements). Chosen so quad-strided scatters hit 4 distinct bank
// octets (conflict-free) and frag reads are <=2-way (free per m136).
#define XO_LD 264  // x / wout stage [64][264] (b128-aligned frags)
#define W_LD 136   // W half-K stage [96][136] (b128-aligned frags)
#define QK_LD 36   // q,k [64][36]  (2xb64 frags)
#define VT_LD 72   // vT [32][72]  (b128-aligned frags)
#define P_LD 68    // p [64][68]   (2xb64 frags)
#define OTR_LD 36  // o transpose buf [64][36] (2xb64 frags)

// LDS element offsets: WR = [0,13056) staging region (W / p / otr / x / wout
// all alias here); q/k/vt live in a disjoint region above it.
#define WR_ELS (96 * W_LD)           // 13056
#define P_OFF 0                      // [0,4352)
#define OTR_OFF (64 * P_LD)          // [4352,6656)
#define Q_OFF WR_ELS                 // 13056
#define K_OFF (Q_OFF + 64 * QK_LD)   // 15360
#define VT_OFF (K_OFF + 64 * QK_LD)  // 17664
#define TOTAL_ELS (VT_OFF + 32 * VT_LD)  // 19968 els = 39936 B -> 4 blocks/CU

static __device__ inline bf16x8 ld8x2(const __bf16* p) {
  bf16x4v lo = *(const bf16x4v*)p;
  bf16x4v hi = *(const bf16x4v*)(p + 4);
  bf16x8 r;
  r[0] = lo[0]; r[1] = lo[1]; r[2] = lo[2]; r[3] = lo[3];
  r[4] = hi[0]; r[5] = hi[1]; r[6] = hi[2]; r[7] = hi[3];
  return r;
}

// ---------------------------------------------------------------- prep -----
__global__ __launch_bounds__(256) void prep_kernel(
    const float* __restrict__ w_qkv, const float* __restrict__ w_out,
    const float* __restrict__ rel_emb, const int* __restrict__ rel_idx,
    __bf16* __restrict__ wqkv_b, __bf16* __restrict__ wout_b,
    float* __restrict__ bias) {
  const float kScale = 0.17677669529663687f;  // 32^-0.5, folded into Wq
  int idx = blockIdx.x * 256 + threadIdx.x;
  if (idx < 196608) {  // w_qkv (768x256) -> bf16, q rows pre-scaled
    float v = w_qkv[idx];
    if (idx < 65536) v *= kScale;
    wqkv_b[idx] = (__bf16)v;
  } else if (idx < 262144) {  // w_out (256x256) -> bf16
    int j = idx - 196608;
    wout_b[j] = (__bf16)w_out[j];
  } else if (idx < 294912) {  // bias_pad[h][64][64], -1e30 beyond 49
    int j = idx - 262144;
    int h = j >> 12, i = (j >> 6) & 63, c = j & 63;
    float v = NEG_BIG;
    if (i < 49 && c < 49) v = rel_emb[rel_idx[i * 49 + c] * 8 + h];
    bias[j] = v;
  }
}

// ---------------------------------------------------------------- main -----
// One block per window, 4 waves; wave w owns M rows [16w,16w+16).
// MFMA 16x16x32 bf16 layouts (HW-verified):
//   A: m=lane&15, k=quad*8+j   B: n=lane&15, k=quad*8+j
//   C/D: col=lane&15, row=quad*4+reg
__global__ __launch_bounds__(256, 4) void attn_kernel(
    const float* __restrict__ x, const __bf16* __restrict__ wqkv,
    const __bf16* __restrict__ wout, const float* __restrict__ bias,
    float* __restrict__ out) {
  __shared__ __attribute__((aligned(16))) __bf16 sm[TOTAL_ELS];

  const int tid = threadIdx.x;
  const int wave = tid >> 6;
  const int lane = tid & 63;
  const int quad = lane >> 4;
  const int l16 = lane & 15;
  const int i0 = wave * 16 + quad * 4;  // C/D row base
  const int am = wave * 16 + l16;       // A/B operand row

  const f32x4 fzero = {0.f, 0.f, 0.f, 0.f};

  // ---- stage x window (49x256 fp32 -> bf16) into [0,16896), zero-pad 49..63
  {
    const float4* xg = (const float4*)(x + (size_t)blockIdx.x * 12544);
    for (int i = tid; i < 3136; i += 256) {
      float4 v = xg[i];
      int row = i >> 6, c4 = (i & 63) << 2;
      bf16x4v t;
      t[0] = (__bf16)v.x; t[1] = (__bf16)v.y; t[2] = (__bf16)v.z; t[3] = (__bf16)v.w;
      *(bf16x4v*)&sm[row * XO_LD + c4] = t;
    }
    bf16x4v z;
    z[0] = z[1] = z[2] = z[3] = (__bf16)0.0f;
    for (int i = tid; i < 960; i += 256) {
      int row = 49 + (i >> 6), c4 = (i & 63) << 2;
      *(bf16x4v*)&sm[row * XO_LD + c4] = z;
    }
  }
  __syncthreads();

  // ---- preload x A-fragments (K=256 -> 8 frags), reused for all 8 heads
  bf16x8 afr[8];
#pragma unroll
  for (int kk = 0; kk < 8; ++kk)
    afr[kk] = *(const bf16x8*)&sm[am * XO_LD + kk * 32 + quad * 8];

  bf16x8 ofr[8];  // per-head out-proj A-fragments, gathered after each PV

  // ---- per-head fused attention
  for (int h = 0; h < 8; ++h) {
    f32x4 acc[6];
#pragma unroll
    for (int t = 0; t < 6; ++t) acc[t] = fzero;

    // qkv GEMM: C(64x96) = x(64x256) @ W^T, staged in two K=128 halves
#pragma unroll
    for (int kh = 0; kh < 2; ++kh) {
      __syncthreads();  // staging region fully consumed by all waves
      for (int i = tid; i < 1536; i += 256) {
        int lr = i >> 4, c = (i & 15) * 8;
        int grow = (lr >> 5) * 256 + h * 32 + (lr & 31);  // q|k|v row
        *(bf16x8*)&sm[lr * W_LD + c] =
            *(const bf16x8*)&wqkv[grow * 256 + kh * 128 + c];
      }
      __syncthreads();
#pragma unroll
      for (int k2 = 0; k2 < 4; ++k2) {
        bf16x8 a = afr[kh * 4 + k2];
#pragma unroll
        for (int t = 0; t < 6; ++t) {
          bf16x8 b = *(const bf16x8*)&sm[(t * 16 + l16) * W_LD + k2 * 32 + quad * 8];
          acc[t] = MFMA(a, b, acc[t]);
        }
      }
    }

    // bias prefetch into regs (global loads overlap the scatter below)
    f32x4 sim[4];
    {
      const float* bb = bias + (h << 12);
#pragma unroll
      for (int nt = 0; nt < 4; ++nt)
#pragma unroll
        for (int r = 0; r < 4; ++r) sim[nt][r] = bb[(i0 + r) * 64 + nt * 16 + l16];
    }

    // scatter q,k row-major and v transposed (disjoint region: no sync needed
    // vs other waves' qkv MFMAs which only read the W region)
#pragma unroll
    for (int t = 0; t < 2; ++t) {
#pragma unroll
      for (int r = 0; r < 4; ++r) {
        sm[Q_OFF + (i0 + r) * QK_LD + t * 16 + l16] = (__bf16)acc[t][r];
        sm[K_OFF + (i0 + r) * QK_LD + t * 16 + l16] = (__bf16)acc[2 + t][r];
      }
      bf16x4v pv;
#pragma unroll
      for (int r = 0; r < 4; ++r) pv[r] = (__bf16)acc[4 + t][r];
      *(bf16x4v*)&sm[VT_OFF + (t * 16 + l16) * VT_LD + i0] = pv;
    }
    __syncthreads();  // D1: q/k/vt visible

    // sim = q.k^T + bias (acc initialized from bias regs; K=32 -> 1 MFMA/tile)
    {
      bf16x8 a = ld8x2(&sm[Q_OFF + am * QK_LD + quad * 8]);
#pragma unroll
      for (int nt = 0; nt < 4; ++nt) {
        bf16x8 b = ld8x2(&sm[K_OFF + (nt * 16 + l16) * QK_LD + quad * 8]);
        sim[nt] = MFMA(a, b, sim[nt]);
      }
    }

    // row softmax: row lives in one 16-lane quad -> shfl_xor 1,2,4,8
#pragma unroll
    for (int r = 0; r < 4; ++r) {
      float mx = fmaxf(fmaxf(sim[0][r], sim[1][r]), fmaxf(sim[2][r], sim[3][r]));
      mx = fmaxf(mx, __shfl_xor(mx, 1));
      mx = fmaxf(mx, __shfl_xor(mx, 2));
      mx = fmaxf(mx, __shfl_xor(mx, 4));
      mx = fmaxf(mx, __shfl_xor(mx, 8));
      float e0 = __expf(sim[0][r] - mx), e1 = __expf(sim[1][r] - mx);
      float e2 = __expf(sim[2][r] - mx), e3 = __expf(sim[3][r] - mx);
      float sum = e0 + e1 + e2 + e3;
      sum += __shfl_xor(sum, 1);
      sum += __shfl_xor(sum, 2);
      sum += __shfl_xor(sum, 4);
      sum += __shfl_xor(sum, 8);
      float rs = 1.0f / sum;
      int row = i0 + r;
      sm[P_OFF + row * P_LD + l16] = (__bf16)(e0 * rs);
      sm[P_OFF + row * P_LD + 16 + l16] = (__bf16)(e1 * rs);
      sm[P_OFF + row * P_LD + 32 + l16] = (__bf16)(e2 * rs);
      sm[P_OFF + row * P_LD + 48 + l16] = (__bf16)(e3 * rs);
    }
    __syncthreads();  // D2: p visible

    // o_h = P(64x64) @ V(64x32)
    f32x4 oa[2];
    oa[0] = fzero;
    oa[1] = fzero;
#pragma unroll
    for (int kk = 0; kk < 2; ++kk) {
      bf16x8 a = ld8x2(&sm[P_OFF + am * P_LD + kk * 32 + quad * 8]);
#pragma unroll
      for (int t = 0; t < 2; ++t) {
        bf16x8 b = *(const bf16x8*)&sm[VT_OFF + (t * 16 + l16) * VT_LD + kk * 32 + quad * 8];
        oa[t] = MFMA(a, b, oa[t]);
      }
    }
    // C-layout -> A-layout round trip for the out-proj fragment (otr disjoint
    // from p/vt being read by other waves)
#pragma unroll
    for (int t = 0; t < 2; ++t)
#pragma unroll
      for (int r = 0; r < 4; ++r)
        sm[OTR_OFF + (i0 + r) * OTR_LD + t * 16 + l16] = (__bf16)oa[t][r];
    __syncthreads();  // D3: otr visible
    ofr[h] = ld8x2(&sm[OTR_OFF + am * OTR_LD + quad * 8]);
    // next head's loop-top sync protects the staging region reuse
  }

  // ---- out projection: out(64x256) = o @ w_out^T; stage 64 wout rows/round
  for (int rr = 0; rr < 4; ++rr) {
    __syncthreads();  // rr=0: ofr gathers done; rr>0: prev B-frag reads done
    for (int i = tid; i < 2048; i += 256) {
      int lr = i >> 5, c = (i & 31) * 8;
      *(bf16x8*)&sm[lr * XO_LD + c] = *(const bf16x8*)&wout[(rr * 64 + lr) * 256 + c];
    }
    __syncthreads();
#pragma unroll
    for (int e2 = 0; e2 < 2; ++e2) {
      f32x4 fa[2];
      fa[0] = fzero;
      fa[1] = fzero;
#pragma unroll
      for (int kk = 0; kk < 8; ++kk) {
        bf16x8 a = ofr[kk];
#pragma unroll
        for (int t = 0; t < 2; ++t) {
          bf16x8 b = *(const bf16x8*)&sm[(e2 * 32 + t * 16 + l16) * XO_LD + kk * 32 + quad * 8];
          fa[t] = MFMA(a, b, fa[t]);
        }
      }
      float* ob = out + (size_t)blockIdx.x * 12544 + (rr * 2 + e2) * 32;
#pragma unroll
      for (int t = 0; t < 2; ++t)
#pragma unroll
        for (int r = 0; r < 4; ++r) {
          int row = i0 + r;
          if (row < 49) ob[row * 256 + t * 16 + l16] = fa[t][r];
        }
    }
  }
}

// ---------------------------------------------------------------- launch ---
extern "C" void kernel_launch(void* const* d_in, const int* in_sizes, int n_in,
                              void* d_out, int out_size, void* d_ws, size_t ws_size,
                              hipStream_t stream) {
  (void)in_sizes; (void)n_in; (void)out_size; (void)ws_size;
  const float* x = (const float*)d_in[0];
  const float* w_qkv = (const float*)d_in[1];
  const float* w_out = (const float*)d_in[2];
  const float* rel_emb = (const float*)d_in[3];
  const int* rel_idx = (const int*)d_in[4];
  float* out = (float*)d_out;

  char* ws = (char*)d_ws;
  __bf16* wqkv_b = (__bf16*)ws;             // 768*256*2 = 393216 B
  __bf16* wout_b = (__bf16*)(ws + 393216);  // 256*256*2 = 131072 B
  float* bias = (float*)(ws + 524288);      // 8*64*64*4 = 131072 B

  prep_kernel<<<1152, 256, 0, stream>>>(w_qkv, w_out, rel_emb, rel_idx,
                                        wqkv_b, wout_b, bias);
  attn_kernel<<<4096, 256, 0, stream>>>(x, wqkv_b, wout_b, bias, out);
}